// Round 2
// baseline (398.729 us; speedup 1.0000x reference)
//
#include <hip/hip_runtime.h>

// NCC forces, 256^3 fp32, 5x5x5 zero-padded box window, symmetric gradients.
// v2: single barrier per z-step (raw s_barrier, lgkm-only drain -> global
//     prefetch spans a full iteration), RS=5 raw ring with odd stride 41
//     (bank-parity mixing), double-buffered field-interleaved ytmp[y][x][5]
//     (phase C = 25 consecutive floats from one base -> ds_read2 merged,
//     conflict-free), center-value register z-pipeline (no z+-1 LDS reads),
//     manual 5x unroll with compile-time ring slots (no %5, no history movs).
//
// Ring-slot safety (slot(p) = (p - z0 + 10) % 5, K = i % 5):
//   per step i (plane z = z0-2+i):  A writes s(z+1)=(K+4)%5, issues load z+2
//                                   B reads  s(z)  =(K+3)%5, writes ytmp[i&1]
//                                   BAR
//                                   C reads ytmp[i&1]
//                                   D reads s(z-1)=(K+2)%5 (center pipe push)
//                                           s(z-2)=(K+1)%5 (x/y gradients)
//   Window (bar_i .. bar_{i+1}) = { C_i, D_i, A_{i+1}, B_{i+1} }:
//     A_{i+1} writes s(z+2)=K%5 ; readers in window: D_i {K+1,K+2}, B_{i+1}
//     {K+4} -> disjoint. B_{i+1} reads s(z+1) written by A_i (before bar_i).
//     Slot K+1 (= plane zc) is only overwritten at A_{i+2}, after bar_{i+1},
//     so D_i's +-1 neighbor reads are safe. ytmp double buffer splits
//     B_{i+1} writes from C_i reads.

#define DIM 256
#define TX  32
#define TY  8
#define ZCH 64
#define PXA 41   // odd LDS row stride: mixes bank parity across rows
#define PY  12
#define NT  256
#define RS  5
#define YW  40
#define NF  5

#define LDS_BAR() asm volatile("s_waitcnt lgkmcnt(0)\n\ts_barrier" ::: "memory")

#define STEP(K, I, ISSUE, COMMIT) do {                                         \
    constexpr int sZ   = ((K) + 3) % RS;                                       \
    constexpr int sZP  = ((K) + 4) % RS;                                       \
    constexpr int sZM1 = ((K) + 2) % RS;                                       \
    constexpr int sZM2 = ((K) + 1) % RS;                                       \
    const int i_ = (I);                                                        \
    /* A: commit prefetched plane z+1, issue load of plane z+2 (= z0+i) */     \
    if (pfAct) {                                                               \
        if (COMMIT) {                                                          \
            float* d_ = praw + (sZP * PY + prow) * PXA + pcol;                 \
            d_[0] = pf.x; d_[1] = pf.y; d_[2] = pf.z; d_[3] = pf.w;            \
        }                                                                      \
        if (ISSUE) {                                                           \
            float4 v_ = make_float4(0.f, 0.f, 0.f, 0.f);                       \
            if ((z0 + i_) < DIM && pxyOk)                                      \
                v_ = *(const float4*)pcur;                                     \
            pcur += (size_t)(DIM * DIM);                                       \
            pf = v_;                                                           \
        }                                                                      \
    }                                                                          \
    const int b_ = i_ & 1;                                                     \
    /* B: y-direction 5-wide box sums of plane z, cols 2..37 (pairs) */        \
    if (bAct) {                                                                \
        float sA0=0.f,sA1=0.f,sB0=0.f,sB1=0.f,sAA0=0.f,sAA1=0.f;               \
        float sBB0=0.f,sBB1=0.f,sAB0=0.f,sAB1=0.f;                             \
        _Pragma("unroll")                                                      \
        for (int dy = 0; dy < 5; ++dy) {                                       \
            const float aI0 = rawI[sZ][brow + dy][bcol];                       \
            const float aI1 = rawI[sZ][brow + dy][bcol + 1];                   \
            const float aR0 = rawR[sZ][brow + dy][bcol];                       \
            const float aR1 = rawR[sZ][brow + dy][bcol + 1];                   \
            sA0 += aI0; sA1 += aI1; sB0 += aR0; sB1 += aR1;                    \
            sAA0 = fmaf(aI0, aI0, sAA0); sAA1 = fmaf(aI1, aI1, sAA1);          \
            sBB0 = fmaf(aR0, aR0, sBB0); sBB1 = fmaf(aR1, aR1, sBB1);          \
            sAB0 = fmaf(aI0, aR0, sAB0); sAB1 = fmaf(aI1, aR1, sAB1);          \
        }                                                                      \
        float* yp_ = &ytmp[b_][brow][bcol][0];                                 \
        yp_[0] = sA0; yp_[1] = sB0; yp_[2] = sAA0; yp_[3] = sBB0;              \
        yp_[4] = sAB0;                                                         \
        yp_[5] = sA1; yp_[6] = sB1; yp_[7] = sAA1; yp_[8] = sBB1;              \
        yp_[9] = sAB1;                                                         \
    }                                                                          \
    LDS_BAR();                                                                 \
    /* C: x-direction box sums -- 25 consecutive floats, one base vaddr */     \
    float n_[NF];                                                              \
    {                                                                          \
        const float* yb_ = &ytmp[b_][ty][tx + 2][0];                           \
        _Pragma("unroll")                                                      \
        for (int f = 0; f < NF; ++f)                                           \
            n_[f] = yb_[f] + yb_[f+5] + yb_[f+10] + yb_[f+15] + yb_[f+20];     \
    }                                                                          \
    /* center register pipeline: push plane z-1 */                             \
    cIm = cI0; cI0 = cIp; cIp = rawI[sZM1][ly][lx];                            \
    cRm = cR0; cR0 = cRp; cRp = rawR[sZM1][ly][lx];                            \
    /* D: finalize output plane zc = z-2 */                                    \
    if (i_ >= 4) {                                                             \
        const int zc = z0 - 4 + i_;                                            \
        float zs[NF];                                                          \
        _Pragma("unroll")                                                      \
        for (int f = 0; f < NF; ++f)                                           \
            zs[f] = H[((K)+1)%RS][f] + H[((K)+2)%RS][f] + H[((K)+3)%RS][f]     \
                  + H[((K)+4)%RS][f] + n_[f];                                  \
        const float m     = zs[0] * (1.0f / 125.0f);                           \
        const float var_r = zs[3] - 2.0f * m * zs[1] + 125.0f * m * m;         \
        const float var_i = zs[2] - 2.0f * m * zs[0] + 125.0f * m * m;         \
        const float cross = zs[4] - m * zs[0] - m * zs[1] + 125.0f * m * m;    \
        float giz, grz;                                                        \
        if (zc == 0)            { giz = cIp - cI0; grz = cRp - cR0; }          \
        else if (zc == DIM - 1) { giz = cI0 - cIm; grz = cR0 - cRm; }          \
        else { giz = 0.5f * (cIp - cIm); grz = 0.5f * (cRp - cRm); }           \
        const float iyp = rawI[sZM2][ly + 1][lx], iym = rawI[sZM2][ly - 1][lx];\
        const float ryp = rawR[sZM2][ly + 1][lx], rym = rawR[sZM2][ly - 1][lx];\
        const float ixp = rawI[sZM2][ly][lx + 1], ixm = rawI[sZM2][ly][lx - 1];\
        const float rxp = rawR[sZM2][ly][lx + 1], rxm = rawR[sZM2][ly][lx - 1];\
        float giy, gry;                                                        \
        if (gy == 0)            { giy = iyp - cI0; gry = ryp - cR0; }          \
        else if (gy == DIM - 1) { giy = cI0 - iym; gry = cR0 - rym; }          \
        else { giy = 0.5f * (iyp - iym); gry = 0.5f * (ryp - rym); }           \
        float gix, grx;                                                        \
        if (gx == 0)            { gix = ixp - cI0; grx = rxp - cR0; }          \
        else if (gx == DIM - 1) { gix = cI0 - ixm; grx = cR0 - rxm; }          \
        else { gix = 0.5f * (ixp - ixm); grx = 0.5f * (rxp - rxm); }           \
        const float inv_d = __builtin_amdgcn_rcpf(fmaf(var_i, var_r, 1e-6f));  \
        const float inv_r = __builtin_amdgcn_rcpf(var_r);                      \
        const float factor = 2.0f * cross * inv_d * (cI0 - cross * inv_r * cR0);\
        const size_t CS    = (size_t)DIM * DIM * DIM;                          \
        const size_t base_ = ((size_t)zc * DIM + gy) * DIM + gx;               \
        __builtin_nontemporal_store(-factor * 0.5f * (giz + grz),              \
                                    &gOut[base_]);                             \
        __builtin_nontemporal_store(-factor * 0.5f * (giy + gry),              \
                                    &gOut[base_ + CS]);                        \
        __builtin_nontemporal_store(-factor * 0.5f * (gix + grx),              \
                                    &gOut[base_ + 2 * CS]);                    \
    }                                                                          \
    /* static circular z-history: no shift movs */                             \
    _Pragma("unroll")                                                          \
    for (int f = 0; f < NF; ++f) H[(K)][f] = n_[f];                            \
} while (0)

__global__ __launch_bounds__(NT, 4) void ncc_forces_kernel(
    const float* __restrict__ gI,
    const float* __restrict__ gR,
    float* __restrict__ gOut)
{
    __shared__ float rawI[RS][PY][PXA];
    __shared__ float rawR[RS][PY][PXA];
    __shared__ float ytmp[2][TY][YW][NF];   // [buf][y][x][field], x-stride 5 (odd)

    const int t  = threadIdx.x;
    const int tx = t & 31;
    const int ty = t >> 5;
    const int x0 = blockIdx.x * TX;
    const int y0 = blockIdx.y * TY;
    const int z0 = blockIdx.z * ZCH;

    // prefetch roles: threads 0..119 load I, 128..247 load R (one float4 each)
    const bool pfI   = (t < 120);
    const bool pfR   = (t >= 128 && t < 248);
    const bool pfAct = pfI || pfR;
    const int  pid   = pfI ? t : (t - 128);
    const int  prow  = pid / 10;
    const int  pcol  = (pid - prow * 10) * 4;
    const int  pgy   = y0 - 2 + prow;
    const int  pgx   = x0 - 4 + pcol;
    const float* pbase = pfI ? gI : gR;
    float*       praw  = pfI ? &rawI[0][0][0] : &rawR[0][0][0];
    const bool   pxyOk = ((unsigned)pgy < DIM) && ((unsigned)pgx < DIM);
    const size_t pgoff = pxyOk ? ((size_t)pgy * DIM + pgx) : 0;

    // y-box role: 144 threads, column pairs covering cols 2..37 only
    const bool bAct = (t < 144);
    const int  brow = t / 18;
    const int  bcol = 2 + (t - brow * 18) * 2;

    const int gy = y0 + ty;
    const int gx = x0 + tx;
    const int ly = ty + 2, lx = tx + 4;

    float4 pf = make_float4(0.f, 0.f, 0.f, 0.f);
    const float* pcur = pbase + (size_t)z0 * (DIM * DIM) + pgoff;  // plane z0+i at step i

    float H[RS][NF];
    #pragma unroll
    for (int a = 0; a < RS; ++a)
        #pragma unroll
        for (int f = 0; f < NF; ++f) H[a][f] = 0.f;
    float cIm = 0.f, cI0 = 0.f, cIp = 0.f, cRm = 0.f, cR0 = 0.f, cRp = 0.f;

    // prologue: plane z0-2 direct to slot 3; plane z0-1 into pf regs
    if (pfAct) {
        float4 v = make_float4(0.f, 0.f, 0.f, 0.f);
        if ((z0 - 2) >= 0 && pxyOk)
            v = *(const float4*)(pbase + (size_t)(z0 - 2) * (DIM * DIM) + pgoff);
        float* d0 = praw + (3 * PY + prow) * PXA + pcol;
        d0[0] = v.x; d0[1] = v.y; d0[2] = v.z; d0[3] = v.w;
        float4 w = make_float4(0.f, 0.f, 0.f, 0.f);
        if ((z0 - 1) >= 0 && pxyOk)
            w = *(const float4*)(pbase + (size_t)(z0 - 1) * (DIM * DIM) + pgoff);
        pf = w;
    }
    LDS_BAR();

    // 68 steps total: 13x5 main + 3-step tail with static slots
    #pragma clang loop unroll(disable)
    for (int ii = 0; ii < 65; ii += 5) {
        STEP(0, ii + 0, true, true);
        STEP(1, ii + 1, true, true);
        STEP(2, ii + 2, true, true);
        STEP(3, ii + 3, true, true);
        STEP(4, ii + 4, true, true);
    }
    STEP(0, 65, true,  true);   // load z0+65 (needed by B at i=67)
    STEP(1, 66, false, true);   // commit z0+65; no more loads
    STEP(2, 67, false, false);  // last output plane zc = z0+63
}

extern "C" void kernel_launch(void* const* d_in, const int* in_sizes, int n_in,
                              void* d_out, int out_size, void* d_ws, size_t ws_size,
                              hipStream_t stream) {
    const float* img = (const float*)d_in[0];  // image
    const float* ref = (const float*)d_in[2];  // reference_image
    float* out = (float*)d_out;

    dim3 grid(DIM / TX, DIM / TY, DIM / ZCH);  // 8 x 32 x 4 = 1024 blocks
    ncc_forces_kernel<<<grid, NT, 0, stream>>>(img, ref, out);
}

// Round 3
// 397.489 us; speedup vs baseline: 1.0031x; 1.0031x over previous
//
#include <hip/hip_runtime.h>

// NCC forces, 256^3 fp32, 5x5x5 zero-padded box window, symmetric gradients.
// v3: ZCH 64 -> 32 (grid 2048, 5 resident blocks/CU -- v2 was grid-limited
//     to 4 with occupancy 39%). Everything else identical to v2:
//     single barrier per z-step (raw s_barrier, lgkm-only drain), RS=5 raw
//     ring stride 41, double-buffered field-interleaved ytmp[y][x][5],
//     center-value register z-pipeline, 5x unroll w/ compile-time slots.
//
// Ring-slot safety (slot(p) = (p - z0 + 10) % 5, K = i % 5):
//   per step i (plane z = z0-2+i):  A writes s(z+1)=(K+4)%5, issues load z+2
//                                   B reads  s(z)  =(K+3)%5, writes ytmp[i&1]
//                                   BAR
//                                   C reads ytmp[i&1]
//                                   D reads s(z-1)=(K+2)%5 (center pipe push)
//                                           s(z-2)=(K+1)%5 (x/y gradients)
//   Window (bar_i .. bar_{i+1}) = { C_i, D_i, A_{i+1}, B_{i+1} }:
//     A_{i+1} writes slot K; readers in window: D_i {K+1,K+2}, B_{i+1} {K+4}
//     -> disjoint. Slot K+1 (= plane zc) is only overwritten at A_{i+2},
//     after bar_{i+1}. ytmp double buffer splits B_{i+1} writes / C_i reads.

#define DIM 256
#define TX  32
#define TY  8
#define ZCH 32
#define PXA 41   // odd LDS row stride: mixes bank parity across rows
#define PY  12
#define NT  256
#define RS  5
#define YW  40
#define NF  5

#define LDS_BAR() asm volatile("s_waitcnt lgkmcnt(0)\n\ts_barrier" ::: "memory")

#define STEP(K, I, ISSUE, COMMIT) do {                                         \
    constexpr int sZ   = ((K) + 3) % RS;                                       \
    constexpr int sZP  = ((K) + 4) % RS;                                       \
    constexpr int sZM1 = ((K) + 2) % RS;                                       \
    constexpr int sZM2 = ((K) + 1) % RS;                                       \
    const int i_ = (I);                                                        \
    /* A: commit prefetched plane z+1, issue load of plane z+2 (= z0+i) */     \
    if (pfAct) {                                                               \
        if (COMMIT) {                                                          \
            float* d_ = praw + (sZP * PY + prow) * PXA + pcol;                 \
            d_[0] = pf.x; d_[1] = pf.y; d_[2] = pf.z; d_[3] = pf.w;            \
        }                                                                      \
        if (ISSUE) {                                                           \
            float4 v_ = make_float4(0.f, 0.f, 0.f, 0.f);                       \
            if ((z0 + i_) < DIM && pxyOk)                                      \
                v_ = *(const float4*)pcur;                                     \
            pcur += (size_t)(DIM * DIM);                                       \
            pf = v_;                                                           \
        }                                                                      \
    }                                                                          \
    const int b_ = i_ & 1;                                                     \
    /* B: y-direction 5-wide box sums of plane z, cols 2..37 (pairs) */        \
    if (bAct) {                                                                \
        float sA0=0.f,sA1=0.f,sB0=0.f,sB1=0.f,sAA0=0.f,sAA1=0.f;               \
        float sBB0=0.f,sBB1=0.f,sAB0=0.f,sAB1=0.f;                             \
        _Pragma("unroll")                                                      \
        for (int dy = 0; dy < 5; ++dy) {                                       \
            const float aI0 = rawI[sZ][brow + dy][bcol];                       \
            const float aI1 = rawI[sZ][brow + dy][bcol + 1];                   \
            const float aR0 = rawR[sZ][brow + dy][bcol];                       \
            const float aR1 = rawR[sZ][brow + dy][bcol + 1];                   \
            sA0 += aI0; sA1 += aI1; sB0 += aR0; sB1 += aR1;                    \
            sAA0 = fmaf(aI0, aI0, sAA0); sAA1 = fmaf(aI1, aI1, sAA1);          \
            sBB0 = fmaf(aR0, aR0, sBB0); sBB1 = fmaf(aR1, aR1, sBB1);          \
            sAB0 = fmaf(aI0, aR0, sAB0); sAB1 = fmaf(aI1, aR1, sAB1);          \
        }                                                                      \
        float* yp_ = &ytmp[b_][brow][bcol][0];                                 \
        yp_[0] = sA0; yp_[1] = sB0; yp_[2] = sAA0; yp_[3] = sBB0;              \
        yp_[4] = sAB0;                                                         \
        yp_[5] = sA1; yp_[6] = sB1; yp_[7] = sAA1; yp_[8] = sBB1;              \
        yp_[9] = sAB1;                                                         \
    }                                                                          \
    LDS_BAR();                                                                 \
    /* C: x-direction box sums -- 25 consecutive floats, one base vaddr */     \
    float n_[NF];                                                              \
    {                                                                          \
        const float* yb_ = &ytmp[b_][ty][tx + 2][0];                           \
        _Pragma("unroll")                                                      \
        for (int f = 0; f < NF; ++f)                                           \
            n_[f] = yb_[f] + yb_[f+5] + yb_[f+10] + yb_[f+15] + yb_[f+20];     \
    }                                                                          \
    /* center register pipeline: push plane z-1 */                             \
    cIm = cI0; cI0 = cIp; cIp = rawI[sZM1][ly][lx];                            \
    cRm = cR0; cR0 = cRp; cRp = rawR[sZM1][ly][lx];                            \
    /* D: finalize output plane zc = z-2 */                                    \
    if (i_ >= 4) {                                                             \
        const int zc = z0 - 4 + i_;                                            \
        float zs[NF];                                                          \
        _Pragma("unroll")                                                      \
        for (int f = 0; f < NF; ++f)                                           \
            zs[f] = H[((K)+1)%RS][f] + H[((K)+2)%RS][f] + H[((K)+3)%RS][f]     \
                  + H[((K)+4)%RS][f] + n_[f];                                  \
        const float m     = zs[0] * (1.0f / 125.0f);                           \
        const float var_r = zs[3] - 2.0f * m * zs[1] + 125.0f * m * m;         \
        const float var_i = zs[2] - 2.0f * m * zs[0] + 125.0f * m * m;         \
        const float cross = zs[4] - m * zs[0] - m * zs[1] + 125.0f * m * m;    \
        float giz, grz;                                                        \
        if (zc == 0)            { giz = cIp - cI0; grz = cRp - cR0; }          \
        else if (zc == DIM - 1) { giz = cI0 - cIm; grz = cR0 - cRm; }          \
        else { giz = 0.5f * (cIp - cIm); grz = 0.5f * (cRp - cRm); }           \
        const float iyp = rawI[sZM2][ly + 1][lx], iym = rawI[sZM2][ly - 1][lx];\
        const float ryp = rawR[sZM2][ly + 1][lx], rym = rawR[sZM2][ly - 1][lx];\
        const float ixp = rawI[sZM2][ly][lx + 1], ixm = rawI[sZM2][ly][lx - 1];\
        const float rxp = rawR[sZM2][ly][lx + 1], rxm = rawR[sZM2][ly][lx - 1];\
        float giy, gry;                                                        \
        if (gy == 0)            { giy = iyp - cI0; gry = ryp - cR0; }          \
        else if (gy == DIM - 1) { giy = cI0 - iym; gry = cR0 - rym; }          \
        else { giy = 0.5f * (iyp - iym); gry = 0.5f * (ryp - rym); }           \
        float gix, grx;                                                        \
        if (gx == 0)            { gix = ixp - cI0; grx = rxp - cR0; }          \
        else if (gx == DIM - 1) { gix = cI0 - ixm; grx = cR0 - rxm; }          \
        else { gix = 0.5f * (ixp - ixm); grx = 0.5f * (rxp - rxm); }           \
        const float inv_d = __builtin_amdgcn_rcpf(fmaf(var_i, var_r, 1e-6f));  \
        const float inv_r = __builtin_amdgcn_rcpf(var_r);                      \
        const float factor = 2.0f * cross * inv_d * (cI0 - cross * inv_r * cR0);\
        const size_t CS    = (size_t)DIM * DIM * DIM;                          \
        const size_t base_ = ((size_t)zc * DIM + gy) * DIM + gx;               \
        __builtin_nontemporal_store(-factor * 0.5f * (giz + grz),              \
                                    &gOut[base_]);                             \
        __builtin_nontemporal_store(-factor * 0.5f * (giy + gry),              \
                                    &gOut[base_ + CS]);                        \
        __builtin_nontemporal_store(-factor * 0.5f * (gix + grx),              \
                                    &gOut[base_ + 2 * CS]);                    \
    }                                                                          \
    /* static circular z-history: no shift movs */                             \
    _Pragma("unroll")                                                          \
    for (int f = 0; f < NF; ++f) H[(K)][f] = n_[f];                            \
} while (0)

__global__ __launch_bounds__(NT, 5) void ncc_forces_kernel(
    const float* __restrict__ gI,
    const float* __restrict__ gR,
    float* __restrict__ gOut)
{
    __shared__ float rawI[RS][PY][PXA];
    __shared__ float rawR[RS][PY][PXA];
    __shared__ float ytmp[2][TY][YW][NF];   // [buf][y][x][field], x-stride 5 (odd)

    const int t  = threadIdx.x;
    const int tx = t & 31;
    const int ty = t >> 5;
    const int x0 = blockIdx.x * TX;
    const int y0 = blockIdx.y * TY;
    const int z0 = blockIdx.z * ZCH;

    // prefetch roles: threads 0..119 load I, 128..247 load R (one float4 each)
    const bool pfI   = (t < 120);
    const bool pfR   = (t >= 128 && t < 248);
    const bool pfAct = pfI || pfR;
    const int  pid   = pfI ? t : (t - 128);
    const int  prow  = pid / 10;
    const int  pcol  = (pid - prow * 10) * 4;
    const int  pgy   = y0 - 2 + prow;
    const int  pgx   = x0 - 4 + pcol;
    const float* pbase = pfI ? gI : gR;
    float*       praw  = pfI ? &rawI[0][0][0] : &rawR[0][0][0];
    const bool   pxyOk = ((unsigned)pgy < DIM) && ((unsigned)pgx < DIM);
    const size_t pgoff = pxyOk ? ((size_t)pgy * DIM + pgx) : 0;

    // y-box role: 144 threads, column pairs covering cols 2..37 only
    const bool bAct = (t < 144);
    const int  brow = t / 18;
    const int  bcol = 2 + (t - brow * 18) * 2;

    const int gy = y0 + ty;
    const int gx = x0 + tx;
    const int ly = ty + 2, lx = tx + 4;

    float4 pf = make_float4(0.f, 0.f, 0.f, 0.f);
    const float* pcur = pbase + (size_t)z0 * (DIM * DIM) + pgoff;  // plane z0+i at step i

    float H[RS][NF];
    #pragma unroll
    for (int a = 0; a < RS; ++a)
        #pragma unroll
        for (int f = 0; f < NF; ++f) H[a][f] = 0.f;
    float cIm = 0.f, cI0 = 0.f, cIp = 0.f, cRm = 0.f, cR0 = 0.f, cRp = 0.f;

    // prologue: plane z0-2 direct to slot 3; plane z0-1 into pf regs
    if (pfAct) {
        float4 v = make_float4(0.f, 0.f, 0.f, 0.f);
        if ((z0 - 2) >= 0 && pxyOk)
            v = *(const float4*)(pbase + (size_t)(z0 - 2) * (DIM * DIM) + pgoff);
        float* d0 = praw + (3 * PY + prow) * PXA + pcol;
        d0[0] = v.x; d0[1] = v.y; d0[2] = v.z; d0[3] = v.w;
        float4 w = make_float4(0.f, 0.f, 0.f, 0.f);
        if ((z0 - 1) >= 0 && pxyOk)
            w = *(const float4*)(pbase + (size_t)(z0 - 1) * (DIM * DIM) + pgoff);
        pf = w;
    }
    LDS_BAR();

    // 36 steps total: 6x5 main + 6-step tail with static slots
    #pragma clang loop unroll(disable)
    for (int ii = 0; ii < 30; ii += 5) {
        STEP(0, ii + 0, true, true);
        STEP(1, ii + 1, true, true);
        STEP(2, ii + 2, true, true);
        STEP(3, ii + 3, true, true);
        STEP(4, ii + 4, true, true);
    }
    STEP(0, 30, true,  true);
    STEP(1, 31, true,  true);
    STEP(2, 32, true,  true);
    STEP(3, 33, true,  true);   // issues plane z0+33, last one B needs (i=35)
    STEP(4, 34, false, true);   // commits z0+33; no more loads
    STEP(0, 35, false, false);  // last output plane zc = z0+31
}

extern "C" void kernel_launch(void* const* d_in, const int* in_sizes, int n_in,
                              void* d_out, int out_size, void* d_ws, size_t ws_size,
                              hipStream_t stream) {
    const float* img = (const float*)d_in[0];  // image
    const float* ref = (const float*)d_in[2];  // reference_image
    float* out = (float*)d_out;

    dim3 grid(DIM / TX, DIM / TY, DIM / ZCH);  // 8 x 32 x 8 = 2048 blocks
    ncc_forces_kernel<<<grid, NT, 0, stream>>>(img, ref, out);
}